// Round 9
// baseline (241.723 us; speedup 1.0000x reference)
//
#include <hip/hip_runtime.h>
#include <hip/hip_bf16.h>
#include <math.h>

typedef __attribute__((ext_vector_type(8))) short short8;
typedef __attribute__((ext_vector_type(4))) short short4v;
typedef __attribute__((ext_vector_type(4))) float f32x4;

static __device__ __forceinline__ short f2bf(float f) {
  union { float f; unsigned u; } x;
  x.f = f;
  unsigned r = x.u + 0x7fffu + ((x.u >> 16) & 1u);
  return (short)(r >> 16);
}

#define GLD16(g, l)                                                   \
  __builtin_amdgcn_global_load_lds(                                   \
      (const __attribute__((address_space(1))) void*)(g),             \
      (__attribute__((address_space(3))) void*)(l), 16, 0, 0)
#define BAR() asm volatile("s_barrier" ::: "memory")
#define LGKM0() asm volatile("s_waitcnt lgkmcnt(0)" ::: "memory")
#define LGKM8() asm volatile("s_waitcnt lgkmcnt(8)" ::: "memory")
#define VMC4() asm volatile("s_waitcnt vmcnt(4)" ::: "memory")
#define VMC0() asm volatile("s_waitcnt vmcnt(0)" ::: "memory")

__global__ __launch_bounds__(256) void cvt_f32_bf16(const float* __restrict__ in,
                                                    short* __restrict__ out, int n8) {
  int i = blockIdx.x * 256 + threadIdx.x;
  if (i >= n8) return;
  const float4* p = (const float4*)in + (size_t)i * 2;
  float4 a = p[0], b = p[1];
  short8 o;
  o[0] = f2bf(a.x); o[1] = f2bf(a.y); o[2] = f2bf(a.z); o[3] = f2bf(a.w);
  o[4] = f2bf(b.x); o[5] = f2bf(b.y); o[6] = f2bf(b.z); o[7] = f2bf(b.w);
  *((short8*)out + i) = o;
}

// ---------------------------------------------------------------------------
// C = A * B^T, bf16 MFMA 16x16x32. BM=BN=256, BK=64, 512 threads, 8 waves
// (2M x 4N, wave tile 128x64). m201-style 8-phase schedule: per phase
// { ds_read subtile ; stage 1 half-tile (2 gload_lds) ; barrier ; lgkmcnt(0)
//   ; setprio(1) 16 MFMA setprio(0) ; [vmcnt(4) at ph3/ph7] ; barrier }.
// Buf = K-tile parity (T=2i->buf0, U=2i+1->buf1). Stage windows verified:
// bufX.B free after its ph0-close (all b read in ph0); bufX.A after ph3-close.
// Ledger: steady in-flight 4-12 loads; vmcnt(4) drains exactly next tile.
// LDS row swizzle: 16B slot ^= (row&7) (128-B rows, 8 slots -> 2-way max).
// MODE 2: C fp32 = acc*scale + rel_bias[gc-gr+ml-1] (scores)
// MODE 3: C fp32 = acc (PV)
// MODE 4: fused QKV: 1024-col slice 0 -> Q bf16, 1 -> K bf16, 2 -> V^T
// ---------------------------------------------------------------------------
template <int MODE>
__global__ __launch_bounds__(512) void gemm8p(
    const short* __restrict__ A, const short* __restrict__ Bt,
    void* __restrict__ C0, void* __restrict__ C1, void* __restrict__ C2,
    const float* __restrict__ rel_bias,
    int N, int K, long aZ, long bZ, long cZ, int Cdim, float scale, int ml) {
  __shared__ short sA[2][16384];   // [buf][256 rows x 64 cols]
  __shared__ short sB[2][16384];
  const int tid = threadIdx.x, lane = tid & 63, wid = tid >> 6;
  const int z = blockIdx.z;
  const short* Az = A + (size_t)z * aZ;
  const short* Bz = Bt + (size_t)z * bZ;
  const int brow = blockIdx.x * 256, bcol = blockIdx.y * 256;
  const int wr = wid >> 2, wc = wid & 3;
  const int lrow = lane & 15, kg = lane >> 4;

  // ---- staging addressing: half-tile h rows h*128..+127; load j covers
  // rows j*64 + tid>>3; slot = tid&7 physical; logical = slot ^ (row&7).
  const int t8 = tid >> 3, t7 = tid & 7;
  const int logslot = t7 ^ (t8 & 7);
  const short* aS[2][2];
  const short* bS[2][2];
#pragma unroll
  for (int h = 0; h < 2; ++h)
#pragma unroll
    for (int j = 0; j < 2; ++j) {
      aS[h][j] = Az + (size_t)(brow + h * 128 + j * 64 + t8) * K + logslot * 8;
      bS[h][j] = Bz + (size_t)(bcol + h * 128 + j * 64 + t8) * K + logslot * 8;
    }

  // ---- ds_read addressing (shorts): row*64 + ((ks*4+kg)^(lrow&7))*8
  const int kOff0 = ((0 + kg) ^ (lrow & 7)) * 8;
  const int kOff1 = ((4 + kg) ^ (lrow & 7)) * 8;
  const int rA = (wr * 128 + lrow) * 64;
  const int rB = (wc * 64 + lrow) * 64;

  short* const A0 = &sA[0][0];
  short* const A1 = &sA[1][0];
  short* const B0 = &sB[0][0];
  short* const B1 = &sB[1][0];

  short8 av[2][2], bv[4][2];
  f32x4 acc[8][4] = {};

#define STG_A(BUF, H, T)                                                      \
  do {                                                                        \
    GLD16(aS[H][0] + (size_t)(T) * 64, &sA[BUF][(H) * 8192 + wid * 512]);     \
    GLD16(aS[H][1] + (size_t)(T) * 64, &sA[BUF][(H) * 8192 + 4096 + wid * 512]); \
  } while (0)
#define STG_B(BUF, H, T)                                                      \
  do {                                                                        \
    GLD16(bS[H][0] + (size_t)(T) * 64, &sB[BUF][(H) * 8192 + wid * 512]);     \
    GLD16(bS[H][1] + (size_t)(T) * 64, &sB[BUF][(H) * 8192 + 4096 + wid * 512]); \
  } while (0)
#define RD_APAIR(P, PP)                                                       \
  do {                                                                        \
    av[0][0] = *(const short8*)&(P)[rA + ((PP) * 2 + 0) * 1024 + kOff0];      \
    av[0][1] = *(const short8*)&(P)[rA + ((PP) * 2 + 0) * 1024 + kOff1];      \
    av[1][0] = *(const short8*)&(P)[rA + ((PP) * 2 + 1) * 1024 + kOff0];      \
    av[1][1] = *(const short8*)&(P)[rA + ((PP) * 2 + 1) * 1024 + kOff1];      \
  } while (0)
#define RD_BALL(P)                                                            \
  do {                                                                        \
    _Pragma("unroll") for (int n = 0; n < 4; ++n) {                           \
      bv[n][0] = *(const short8*)&(P)[rB + n * 1024 + kOff0];                 \
      bv[n][1] = *(const short8*)&(P)[rB + n * 1024 + kOff1];                 \
    }                                                                         \
  } while (0)
#define MFMA_PH(PP)                                                           \
  do {                                                                        \
    __builtin_amdgcn_s_setprio(1);                                            \
    _Pragma("unroll") for (int mp = 0; mp < 2; ++mp)                          \
        _Pragma("unroll") for (int n = 0; n < 4; ++n) {                       \
      acc[(PP) * 2 + mp][n] = __builtin_amdgcn_mfma_f32_16x16x32_bf16(        \
          av[mp][0], bv[n][0], acc[(PP) * 2 + mp][n], 0, 0, 0);               \
      acc[(PP) * 2 + mp][n] = __builtin_amdgcn_mfma_f32_16x16x32_bf16(        \
          av[mp][1], bv[n][1], acc[(PP) * 2 + mp][n], 0, 0, 0);               \
    }                                                                         \
    __builtin_amdgcn_s_setprio(0);                                            \
  } while (0)

  // ---- prologue: T0 full (8 loads), U0.B (4). vmcnt(4) drains T0.
  STG_A(0, 0, 0); STG_A(0, 1, 0); STG_B(0, 0, 0); STG_B(0, 1, 0);
  STG_B(1, 0, 1); STG_B(1, 1, 1);
  VMC4();
  BAR();

  const int NIT = K >> 7;  // pairs of K-tiles (K/128), >= 8 here
  for (int i = 0; i < NIT - 1; ++i) {
    const int tU = 2 * i + 1, tV = 2 * i + 2, tW = 2 * i + 3;
    // ph0 (tile T, m01)
    RD_BALL(B0); RD_APAIR(A0, 0);
    STG_A(1, 0, tU);
    LGKM8();
    BAR(); LGKM0(); MFMA_PH(0); BAR();
    // ph1 (m23)
    RD_APAIR(A0, 1); STG_A(1, 1, tU);
    BAR(); LGKM0(); MFMA_PH(1); BAR();
    // ph2 (m45)
    RD_APAIR(A0, 2); STG_B(0, 0, tV);
    BAR(); LGKM0(); MFMA_PH(2); BAR();
    // ph3 (m67); gate: U must be landed for ph4
    RD_APAIR(A0, 3); STG_B(0, 1, tV);
    BAR(); LGKM0(); MFMA_PH(3);
    VMC4();
    BAR();
    // ph4 (tile U, m01)
    RD_BALL(B1); RD_APAIR(A1, 0);
    STG_A(0, 0, tV);
    LGKM8();
    BAR(); LGKM0(); MFMA_PH(0); BAR();
    // ph5 (m23)
    RD_APAIR(A1, 1); STG_A(0, 1, tV);
    BAR(); LGKM0(); MFMA_PH(1); BAR();
    // ph6 (m45)
    RD_APAIR(A1, 2); STG_B(1, 0, tW);
    BAR(); LGKM0(); MFMA_PH(2); BAR();
    // ph7 (m67); gate: V must be landed for next ph0
    RD_APAIR(A1, 3); STG_B(1, 1, tW);
    BAR(); LGKM0(); MFMA_PH(3);
    VMC4();
    BAR();
  }
  // ---- final iteration (T = 2*NIT-2, U = 2*NIT-1): U.A still staged ph0-1
  {
    const int tU = 2 * NIT - 1;
    RD_BALL(B0); RD_APAIR(A0, 0);
    STG_A(1, 0, tU);
    LGKM8();
    BAR(); LGKM0(); MFMA_PH(0); BAR();
    RD_APAIR(A0, 1); STG_A(1, 1, tU);
    BAR(); LGKM0(); MFMA_PH(1); BAR();
    RD_APAIR(A0, 2);
    BAR(); LGKM0(); MFMA_PH(2); BAR();
    RD_APAIR(A0, 3);
    BAR(); LGKM0(); MFMA_PH(3);
    VMC0();
    BAR();
    RD_BALL(B1); RD_APAIR(A1, 0);
    BAR(); LGKM0(); MFMA_PH(0); BAR();
    RD_APAIR(A1, 1);
    BAR(); LGKM0(); MFMA_PH(1); BAR();
    RD_APAIR(A1, 2);
    BAR(); LGKM0(); MFMA_PH(2); BAR();
    RD_APAIR(A1, 3);
    BAR(); LGKM0(); MFMA_PH(3);
  }

  // ---- epilogue
#pragma unroll
  for (int m = 0; m < 8; ++m) {
#pragma unroll
    for (int n = 0; n < 4; ++n) {
#pragma unroll
      for (int r = 0; r < 4; ++r) {
        float v = acc[m][n][r];
        int gr = brow + wr * 128 + m * 16 + kg * 4 + r;
        int gc = bcol + wc * 64 + n * 16 + lrow;
        if constexpr (MODE == 2) {
          int idx = gc - gr + (ml - 1);
          idx = min(max(idx, 0), 2 * ml - 2);
          ((float*)C0 + (size_t)z * cZ)[(size_t)gr * N + gc] =
              v * scale + rel_bias[idx];
        } else if constexpr (MODE == 3) {
          ((float*)C0 + (size_t)z * cZ)[(size_t)gr * N + gc] = v;
        } else {  // MODE 4: fused QKV, 1024-col slices
          int s = gc >> 10, cc = gc & 1023;
          if (s == 0) {
            ((short*)C0)[(size_t)gr * 1024 + cc] = f2bf(v);
          } else if (s == 1) {
            ((short*)C1)[(size_t)gr * 1024 + cc] = f2bf(v);
          } else {
            int b_ = gr / Cdim, c_ = gr % Cdim;
            ((short*)C2)[((size_t)b_ * 1024 + cc) * Cdim + c_] = f2bf(v);
          }
        }
      }
    }
  }
#undef STG_A
#undef STG_B
#undef RD_APAIR
#undef RD_BALL
#undef MFMA_PH
}

// Row softmax in place (rows of 2048) + bf16 copy for the PV GEMM.
__global__ __launch_bounds__(256) void softmax_rows(float* __restrict__ w,
                                                    short* __restrict__ wb, int Cd) {
  const size_t row = blockIdx.x;
  float4* p = (float4*)(w + row * (size_t)Cd);
  const int tid = threadIdx.x;
  float4 v0 = p[tid];
  float4 v1 = p[tid + 256];
  float mx = fmaxf(fmaxf(fmaxf(v0.x, v0.y), fmaxf(v0.z, v0.w)),
                   fmaxf(fmaxf(v1.x, v1.y), fmaxf(v1.z, v1.w)));
#pragma unroll
  for (int o = 32; o; o >>= 1) mx = fmaxf(mx, __shfl_xor(mx, o));
  __shared__ float red[8];
  const int wv = tid >> 6;
  if ((tid & 63) == 0) red[wv] = mx;
  __syncthreads();
  mx = fmaxf(fmaxf(red[0], red[1]), fmaxf(red[2], red[3]));
  v0.x = __expf(v0.x - mx); v0.y = __expf(v0.y - mx);
  v0.z = __expf(v0.z - mx); v0.w = __expf(v0.w - mx);
  v1.x = __expf(v1.x - mx); v1.y = __expf(v1.y - mx);
  v1.z = __expf(v1.z - mx); v1.w = __expf(v1.w - mx);
  float s = v0.x + v0.y + v0.z + v0.w + v1.x + v1.y + v1.z + v1.w;
#pragma unroll
  for (int o = 32; o; o >>= 1) s += __shfl_xor(s, o);
  if ((tid & 63) == 0) red[4 + wv] = s;
  __syncthreads();
  s = red[4] + red[5] + red[6] + red[7];
  float inv = 1.0f / s;
  v0.x *= inv; v0.y *= inv; v0.z *= inv; v0.w *= inv;
  v1.x *= inv; v1.y *= inv; v1.z *= inv; v1.w *= inv;
  p[tid] = v0;
  p[tid + 256] = v1;
  short4v b0, b1;
  b0[0] = f2bf(v0.x); b0[1] = f2bf(v0.y); b0[2] = f2bf(v0.z); b0[3] = f2bf(v0.w);
  b1[0] = f2bf(v1.x); b1[1] = f2bf(v1.y); b1[2] = f2bf(v1.z); b1[3] = f2bf(v1.w);
  short* wrow = wb + row * (size_t)Cd;
  *(short4v*)&wrow[tid * 4] = b0;
  *(short4v*)&wrow[1024 + tid * 4] = b1;
}

extern "C" void kernel_launch(void* const* d_in, const int* in_sizes, int n_in,
                              void* d_out, int out_size, void* d_ws, size_t ws_size,
                              hipStream_t stream) {
  const float* x = (const float*)d_in[0];
  const float* Wq = (const float*)d_in[1];
  const float* Wk = (const float*)d_in[2];
  const float* Wv = (const float*)d_in[3];
  const float* rb = (const float*)d_in[4];

  const int E = 1024;
  const int Mt = in_sizes[0] / E;           // B*C = 8192
  const int Cd = out_size / Mt - E;         // 2048
  const int B = Mt / Cd;                    // 4
  const int ml = (in_sizes[4] + 1) / 2;     // max_len = 2048
  const float scale = 1.0f / sqrtf((float)E);

  // workspace layout (bf16 = short)
  short* xb = (short*)d_ws;                 // Mt*E
  short* wqb = xb + (size_t)Mt * E;         // E*E (Wq,Wk,Wv contiguous = 3072xE)
  short* wkb = wqb + (size_t)E * E;
  short* wvb = wkb + (size_t)E * E;
  short* Qb = wvb + (size_t)E * E;          // Mt*E
  short* Kb = Qb + (size_t)Mt * E;          // Mt*E
  short* Vt = Kb + (size_t)Mt * E;          // B*E*Cd
  short* wbf = Qb;                          // Mt*Cd (reuse Q+K after scores)

  float* outp = (float*)d_out;              // Mt*E
  float* wts = outp + (size_t)Mt * E;       // Mt*Cd

  cvt_f32_bf16<<<(Mt * E) / 2048, 256, 0, stream>>>(x, xb, (Mt * E) / 8);
  cvt_f32_bf16<<<(E * E) / 2048, 256, 0, stream>>>(Wq, wqb, (E * E) / 8);
  cvt_f32_bf16<<<(E * E) / 2048, 256, 0, stream>>>(Wk, wkb, (E * E) / 8);
  cvt_f32_bf16<<<(E * E) / 2048, 256, 0, stream>>>(Wv, wvb, (E * E) / 8);

  dim3 blk(512);
  // fused QKV projection: A = xb (8192x1024), Bt = [Wq;Wk;Wv] (3072x1024)
  gemm8p<4><<<dim3(Mt / 256, 3 * E / 256, 1), blk, 0, stream>>>(
      xb, wqb, Qb, Kb, Vt, nullptr, 3 * E, E, 0, 0, 0, Cd, 0.f, ml);
  // scores = Q K^T * scale + bias (fp32 into weights region)
  gemm8p<2><<<dim3(Cd / 256, Cd / 256, B), blk, 0, stream>>>(
      Qb, Kb, wts, nullptr, nullptr, rb, Cd, E, (long)Cd * E, (long)Cd * E,
      (long)Cd * Cd, Cd, scale, ml);
  softmax_rows<<<Mt, 256, 0, stream>>>(wts, wbf, Cd);
  // out = weights @ V (A = bf16 weights, Bt = V^T)
  gemm8p<3><<<dim3(Cd / 256, E / 256, B), blk, 0, stream>>>(
      wbf, Vt, outp, nullptr, nullptr, nullptr, E, Cd, (long)Cd * Cd,
      (long)E * Cd, (long)Cd * E, Cd, 0.f, ml);
}

// Round 10
// 199.776 us; speedup vs baseline: 1.2100x; 1.2100x over previous
//
#include <hip/hip_runtime.h>
#include <hip/hip_bf16.h>
#include <math.h>

typedef __attribute__((ext_vector_type(8))) short short8;
typedef __attribute__((ext_vector_type(4))) short short4v;
typedef __attribute__((ext_vector_type(4))) float f32x4;

static __device__ __forceinline__ short f2bf(float f) {
  union { float f; unsigned u; } x;
  x.f = f;
  unsigned r = x.u + 0x7fffu + ((x.u >> 16) & 1u);
  return (short)(r >> 16);
}

#define GLD16(g, l)                                                   \
  __builtin_amdgcn_global_load_lds(                                   \
      (const __attribute__((address_space(1))) void*)(g),             \
      (__attribute__((address_space(3))) void*)(l), 16, 0, 0)
#define BAR() asm volatile("s_barrier" ::: "memory")
#define VMCNT6() asm volatile("s_waitcnt vmcnt(6)" ::: "memory")
#define VMCNT0() asm volatile("s_waitcnt vmcnt(0)" ::: "memory")

// fused cast: x, Wq, Wk, Wv -> bf16 in one launch
__global__ __launch_bounds__(256) void cvt_all(
    const float* __restrict__ x, const float* __restrict__ wq,
    const float* __restrict__ wk, const float* __restrict__ wv,
    short* __restrict__ xb, short* __restrict__ wqb,
    short* __restrict__ wkb, short* __restrict__ wvb, int n0, int n1) {
  int i = blockIdx.x * 256 + threadIdx.x;
  const float* src; short* dst; int off;
  if (i < n0) { src = x; dst = xb; off = i; }
  else if (i < n0 + n1) { src = wq; dst = wqb; off = i - n0; }
  else if (i < n0 + 2 * n1) { src = wk; dst = wkb; off = i - n0 - n1; }
  else if (i < n0 + 3 * n1) { src = wv; dst = wvb; off = i - n0 - 2 * n1; }
  else return;
  const float4* p = (const float4*)src + (size_t)off * 2;
  float4 a = p[0], b = p[1];
  short8 o;
  o[0] = f2bf(a.x); o[1] = f2bf(a.y); o[2] = f2bf(a.z); o[3] = f2bf(a.w);
  o[4] = f2bf(b.x); o[5] = f2bf(b.y); o[6] = f2bf(b.z); o[7] = f2bf(b.w);
  *((short8*)dst + off) = o;
}

// ---------------------------------------------------------------------------
// C = A * B^T, bf16 MFMA 16x16x32. BM=256, BN=128, BK=64, 512 threads
// (8 waves 2M x 4N, wave tile 128x32). TRIPLE-buffered LDS (144 KB), 2
// sub-phases/K-tile, vmcnt(6) once per K-tile. XOR-swizzled LDS (both sides).
// Bijective XCD block swizzle (m204): each XCD gets a contiguous bx-major
// chunk of logical tiles -> A-panel locality in its private L2.
// MODE 2: C fp32 = acc*scale + rel_bias[gc-gr+ml-1] (scores)
// MODE 3: C fp32 = acc (PV)
// MODE 4: fused QKV: 1024-col slice 0 -> Q, 1 -> K, 2 -> V (ALL row-major)
// ---------------------------------------------------------------------------
template <int MODE>
__global__ __launch_bounds__(512) void gemm3b(
    const short* __restrict__ A, const short* __restrict__ Bt,
    void* __restrict__ C0, void* __restrict__ C1, void* __restrict__ C2,
    const float* __restrict__ rel_bias,
    int N, int K, long aZ, long bZ, long cZ, int Cdim, float scale, int ml) {
  __shared__ short sA[3][256 * 64];
  __shared__ short sB[3][128 * 64];
  const int tid = threadIdx.x, lane = tid & 63, wid = tid >> 6;

  // bijective XCD swizzle over the flat workgroup id
  const int gx = gridDim.x, gy = gridDim.y;
  const int nwg = gx * gy * (int)gridDim.z;
  const int f = ((int)blockIdx.z * gy + (int)blockIdx.y) * gx + (int)blockIdx.x;
  const int qq = nwg >> 3, rr = nwg & 7;
  const int xcd = f & 7, pos = f >> 3;
  const int lg = (xcd < rr ? xcd * (qq + 1) : rr * (qq + 1) + (xcd - rr) * qq) + pos;
  const int z = lg / (gx * gy);
  const int rem = lg - z * (gx * gy);
  const int bx = rem / gy, by = rem - bx * gy;  // bx-major within a chunk

  const short* Az = A + (size_t)z * aZ;
  const short* Bz = Bt + (size_t)z * bZ;
  const int brow = bx * 256, bcol = by * 128;
  const int wr = wid >> 2, wc = wid & 3;
  const int lrow = lane & 15, kg = lane >> 4;
  const int l8 = lane >> 3, lm8 = lane & 7;
  const int scol = (lm8 ^ l8) * 8;  // pre-swizzled source col (elems)

  const short* aS[2][2];
  int aD[2][2];
#pragma unroll
  for (int h = 0; h < 2; ++h)
#pragma unroll
    for (int j = 0; j < 2; ++j) {
      int c = wid * 2 + j;
      int rb = c * 8 + (c >= 8 ? 64 : 0) + h * 64;
      aS[h][j] = Az + (size_t)(brow + rb + l8) * K + scol;
      aD[h][j] = rb * 64;
    }
  const short* bS[2];
  int bD[2];
#pragma unroll
  for (int h = 0; h < 2; ++h) {
    int rb = wid * 8 + h * 64;
    bS[h] = Bz + (size_t)(bcol + rb + l8) * K + scol;
    bD[h] = rb * 64;
  }

  const int sks0 = ((0 + kg) ^ (lrow & 7)) * 8;
  const int sks1 = ((4 + kg) ^ (lrow & 7)) * 8;
  const int aR = (wr * 128 + lrow) * 64;
  const int bR = (wc * 32 + lrow) * 64;

  short8 a[4][2], b[2][2];
  f32x4 acc[8][2] = {};

  short *pa0 = &sA[0][0], *pa1 = &sA[1][0], *pa2 = &sA[2][0];
  short *pb0 = &sB[0][0], *pb1 = &sB[1][0], *pb2 = &sB[2][0];

#define STG_A(PA, H, T)                                          \
  do {                                                           \
    GLD16(aS[H][0] + (size_t)(T) * 64, (PA) + aD[H][0]);         \
    GLD16(aS[H][1] + (size_t)(T) * 64, (PA) + aD[H][1]);         \
  } while (0)
#define STG_B(PB, H, T) GLD16(bS[H] + (size_t)(T) * 64, (PB) + bD[H])
#define RD_A(PA, MH)                                                          \
  do {                                                                        \
    _Pragma("unroll") for (int mq = 0; mq < 4; ++mq) {                        \
      a[mq][0] = *(const short8*)&(PA)[aR + (MH)*4096 + mq * 1024 + sks0];    \
      a[mq][1] = *(const short8*)&(PA)[aR + (MH)*4096 + mq * 1024 + sks1];    \
    }                                                                         \
  } while (0)
#define RD_B(PB)                                                   \
  do {                                                             \
    _Pragma("unroll") for (int nq = 0; nq < 2; ++nq) {             \
      b[nq][0] = *(const short8*)&(PB)[bR + nq * 1024 + sks0];     \
      b[nq][1] = *(const short8*)&(PB)[bR + nq * 1024 + sks1];     \
    }                                                              \
  } while (0)
#define MFMA16(MH)                                                            \
  do {                                                                        \
    __builtin_amdgcn_s_setprio(1);                                            \
    _Pragma("unroll") for (int mq = 0; mq < 4; ++mq)                          \
        _Pragma("unroll") for (int nq = 0; nq < 2; ++nq) {                    \
      acc[(MH)*4 + mq][nq] = __builtin_amdgcn_mfma_f32_16x16x32_bf16(         \
          a[mq][0], b[nq][0], acc[(MH)*4 + mq][nq], 0, 0, 0);                 \
      acc[(MH)*4 + mq][nq] = __builtin_amdgcn_mfma_f32_16x16x32_bf16(         \
          a[mq][1], b[nq][1], acc[(MH)*4 + mq][nq], 0, 0, 0);                 \
    }                                                                         \
    __builtin_amdgcn_s_setprio(0);                                            \
  } while (0)

  STG_A(pa0, 0, 0); STG_B(pb0, 0, 0); STG_A(pa0, 1, 0); STG_B(pb0, 1, 0);
  STG_A(pa1, 0, 1); STG_B(pb1, 0, 1); STG_A(pa1, 1, 1); STG_B(pb1, 1, 1);
  VMCNT6();
  BAR();

  const int NT = K >> 6;
  for (int t = 0; t < NT - 2; ++t) {
    RD_A(pa0, 0); RD_B(pb0);
    STG_A(pa2, 0, t + 2); STG_B(pb2, 0, t + 2);
    BAR();
    MFMA16(0);
    BAR();
    RD_A(pa0, 1);
    STG_A(pa2, 1, t + 2); STG_B(pb2, 1, t + 2);
    VMCNT6();
    BAR();
    MFMA16(1);
    BAR();
    short* q;
    q = pa0; pa0 = pa1; pa1 = pa2; pa2 = q;
    q = pb0; pb0 = pb1; pb1 = pb2; pb2 = q;
  }
  RD_A(pa0, 0); RD_B(pb0);
  BAR(); MFMA16(0); BAR();
  RD_A(pa0, 1);
  VMCNT0();
  BAR(); MFMA16(1); BAR();
  RD_A(pa1, 0); RD_B(pb1);
  BAR(); MFMA16(0); BAR();
  RD_A(pa1, 1);
  BAR(); MFMA16(1);

#pragma unroll
  for (int m = 0; m < 8; ++m) {
#pragma unroll
    for (int n = 0; n < 2; ++n) {
#pragma unroll
      for (int r = 0; r < 4; ++r) {
        float v = acc[m][n][r];
        int gr = brow + wr * 128 + m * 16 + kg * 4 + r;
        int gc = bcol + wc * 32 + n * 16 + lrow;
        if constexpr (MODE == 2) {
          int idx = gc - gr + (ml - 1);
          idx = min(max(idx, 0), 2 * ml - 2);
          ((float*)C0 + (size_t)z * cZ)[(size_t)gr * N + gc] =
              v * scale + rel_bias[idx];
        } else if constexpr (MODE == 3) {
          ((float*)C0 + (size_t)z * cZ)[(size_t)gr * N + gc] = v;
        } else {  // MODE 4: fused QKV, 1024-col slices, ALL row-major
          int s = gc >> 10, cc = gc & 1023;
          short* dst = (s == 0) ? (short*)C0 : (s == 1) ? (short*)C1 : (short*)C2;
          dst[(size_t)gr * 1024 + cc] = f2bf(v);
        }
      }
    }
  }
#undef STG_A
#undef STG_B
#undef RD_A
#undef RD_B
#undef MFMA16
}

// 64x64 LDS tile transpose: vin[b][c][e] (row-major [Cd][E]) -> vout[b][e][c]
__global__ __launch_bounds__(256) void transpose_v(const short* __restrict__ vin,
                                                   short* __restrict__ vout,
                                                   int Cd, int E) {
  __shared__ short t[64][72];
  const int c0 = blockIdx.x * 64, e0 = blockIdx.y * 64, b = blockIdx.z;
  const int tid = threadIdx.x;
  const int cr = tid >> 2;             // 0..63: input row within tile
  const int ec = (tid & 3) * 16;       // input col chunk
  const short* src = vin + ((size_t)b * Cd + c0 + cr) * E + e0 + ec;
  short8 v0 = *(const short8*)src;
  short8 v1 = *(const short8*)(src + 8);
#pragma unroll
  for (int j = 0; j < 8; ++j) t[ec + j][cr] = v0[j];
#pragma unroll
  for (int j = 0; j < 8; ++j) t[ec + 8 + j][cr] = v1[j];
  __syncthreads();
  const int er = tid >> 2;             // output row (e-dim)
  const int cc = (tid & 3) * 16;       // output col chunk (c-dim)
  short* dst = vout + ((size_t)b * E + e0 + er) * Cd + c0 + cc;
  *(short8*)dst = *(const short8*)&t[er][cc];
  *(short8*)(dst + 8) = *(const short8*)&t[er][cc + 8];
}

// Row softmax in place (rows of 2048) + bf16 copy for the PV GEMM.
__global__ __launch_bounds__(256) void softmax_rows(float* __restrict__ w,
                                                    short* __restrict__ wb, int Cd) {
  const size_t row = blockIdx.x;
  float4* p = (float4*)(w + row * (size_t)Cd);
  const int tid = threadIdx.x;
  float4 v0 = p[tid];
  float4 v1 = p[tid + 256];
  float mx = fmaxf(fmaxf(fmaxf(v0.x, v0.y), fmaxf(v0.z, v0.w)),
                   fmaxf(fmaxf(v1.x, v1.y), fmaxf(v1.z, v1.w)));
#pragma unroll
  for (int o = 32; o; o >>= 1) mx = fmaxf(mx, __shfl_xor(mx, o));
  __shared__ float red[8];
  const int wv = tid >> 6;
  if ((tid & 63) == 0) red[wv] = mx;
  __syncthreads();
  mx = fmaxf(fmaxf(red[0], red[1]), fmaxf(red[2], red[3]));
  v0.x = __expf(v0.x - mx); v0.y = __expf(v0.y - mx);
  v0.z = __expf(v0.z - mx); v0.w = __expf(v0.w - mx);
  v1.x = __expf(v1.x - mx); v1.y = __expf(v1.y - mx);
  v1.z = __expf(v1.z - mx); v1.w = __expf(v1.w - mx);
  float s = v0.x + v0.y + v0.z + v0.w + v1.x + v1.y + v1.z + v1.w;
#pragma unroll
  for (int o = 32; o; o >>= 1) s += __shfl_xor(s, o);
  if ((tid & 63) == 0) red[4 + wv] = s;
  __syncthreads();
  s = red[4] + red[5] + red[6] + red[7];
  float inv = 1.0f / s;
  v0.x *= inv; v0.y *= inv; v0.z *= inv; v0.w *= inv;
  v1.x *= inv; v1.y *= inv; v1.z *= inv; v1.w *= inv;
  p[tid] = v0;
  p[tid + 256] = v1;
  short4v b0, b1;
  b0[0] = f2bf(v0.x); b0[1] = f2bf(v0.y); b0[2] = f2bf(v0.z); b0[3] = f2bf(v0.w);
  b1[0] = f2bf(v1.x); b1[1] = f2bf(v1.y); b1[2] = f2bf(v1.z); b1[3] = f2bf(v1.w);
  short* wrow = wb + row * (size_t)Cd;
  *(short4v*)&wrow[tid * 4] = b0;
  *(short4v*)&wrow[1024 + tid * 4] = b1;
}

extern "C" void kernel_launch(void* const* d_in, const int* in_sizes, int n_in,
                              void* d_out, int out_size, void* d_ws, size_t ws_size,
                              hipStream_t stream) {
  const float* x = (const float*)d_in[0];
  const float* Wq = (const float*)d_in[1];
  const float* Wk = (const float*)d_in[2];
  const float* Wv = (const float*)d_in[3];
  const float* rb = (const float*)d_in[4];

  const int E = 1024;
  const int Mt = in_sizes[0] / E;           // B*C = 8192
  const int Cd = out_size / Mt - E;         // 2048
  const int B = Mt / Cd;                    // 4
  const int ml = (in_sizes[4] + 1) / 2;     // max_len = 2048
  const float scale = 1.0f / sqrtf((float)E);

  // workspace layout (bf16 = short), 70 MB
  short* xb = (short*)d_ws;                 // Mt*E (dead after QKV -> Vt)
  short* wqb = xb + (size_t)Mt * E;         // E*E x3
  short* wkb = wqb + (size_t)E * E;
  short* wvb = wkb + (size_t)E * E;
  short* Qb = wvb + (size_t)E * E;          // Mt*E
  short* Kb = Qb + (size_t)Mt * E;          // Mt*E
  short* Vrow = Kb + (size_t)Mt * E;        // Mt*E (V row-major)
  short* Vt = xb;                           // B*E*Cd = Mt*E (reuse xb)
  short* wbf = Qb;                          // Mt*Cd (reuse Q+K after scores)

  float* outp = (float*)d_out;              // Mt*E
  float* wts = outp + (size_t)Mt * E;       // Mt*Cd

  const int n0 = (Mt * E) / 8, n1 = (E * E) / 8;
  cvt_all<<<(n0 + 3 * n1 + 255) / 256, 256, 0, stream>>>(
      x, Wq, Wk, Wv, xb, wqb, wkb, wvb, n0, n1);

  dim3 blk(512);
  // fused QKV projection: A = xb (8192x1024), Bt = [Wq;Wk;Wv] (3072x1024)
  gemm3b<4><<<dim3(Mt / 256, 3 * E / 128, 1), blk, 0, stream>>>(
      xb, wqb, Qb, Kb, Vrow, nullptr, 3 * E, E, 0, 0, 0, Cd, 0.f, ml);
  // scores = Q K^T * scale + bias (fp32 into weights region)
  gemm3b<2><<<dim3(Cd / 256, Cd / 128, B), blk, 0, stream>>>(
      Qb, Kb, wts, nullptr, nullptr, rb, Cd, E, (long)Cd * E, (long)Cd * E,
      (long)Cd * Cd, Cd, scale, ml);
  softmax_rows<<<Mt, 256, 0, stream>>>(wts, wbf, Cd);
  // V -> V^T (xb region is dead now)
  transpose_v<<<dim3(Cd / 64, E / 64, B), 256, 0, stream>>>(Vrow, Vt, Cd, E);
  // out = weights @ V (A = bf16 weights, Bt = V^T)
  gemm3b<3><<<dim3(Cd / 256, E / 128, B), blk, 0, stream>>>(
      wbf, Vt, outp, nullptr, nullptr, nullptr, E, Cd, (long)Cd * Cd,
      (long)E * Cd, (long)Cd * E, Cd, 0.f, ml);
}

// Round 11
// 198.292 us; speedup vs baseline: 1.2190x; 1.0075x over previous
//
#include <hip/hip_runtime.h>
#include <hip/hip_bf16.h>
#include <math.h>

typedef __attribute__((ext_vector_type(8))) short short8;
typedef __attribute__((ext_vector_type(4))) short short4v;
typedef __attribute__((ext_vector_type(4))) float f32x4;

static __device__ __forceinline__ short f2bf(float f) {
  union { float f; unsigned u; } x;
  x.f = f;
  unsigned r = x.u + 0x7fffu + ((x.u >> 16) & 1u);
  return (short)(r >> 16);
}

#define GLD16(g, l)                                                   \
  __builtin_amdgcn_global_load_lds(                                   \
      (const __attribute__((address_space(1))) void*)(g),             \
      (__attribute__((address_space(3))) void*)(l), 16, 0, 0)
#define BAR() asm volatile("s_barrier" ::: "memory")
#define VMCNT4() asm volatile("s_waitcnt vmcnt(4)" ::: "memory")
#define VMCNT0() asm volatile("s_waitcnt vmcnt(0)" ::: "memory")

// fused cast: x, Wq, Wk, Wv -> bf16 in one launch
__global__ __launch_bounds__(256) void cvt_all(
    const float* __restrict__ x, const float* __restrict__ wq,
    const float* __restrict__ wk, const float* __restrict__ wv,
    short* __restrict__ xb, short* __restrict__ wqb,
    short* __restrict__ wkb, short* __restrict__ wvb, int n0, int n1) {
  int i = blockIdx.x * 256 + threadIdx.x;
  const float* src; short* dst; int off;
  if (i < n0) { src = x; dst = xb; off = i; }
  else if (i < n0 + n1) { src = wq; dst = wqb; off = i - n0; }
  else if (i < n0 + 2 * n1) { src = wk; dst = wkb; off = i - n0 - n1; }
  else if (i < n0 + 3 * n1) { src = wv; dst = wvb; off = i - n0 - 2 * n1; }
  else return;
  const float4* p = (const float4*)src + (size_t)off * 2;
  float4 a = p[0], b = p[1];
  short8 o;
  o[0] = f2bf(a.x); o[1] = f2bf(a.y); o[2] = f2bf(a.z); o[3] = f2bf(a.w);
  o[4] = f2bf(b.x); o[5] = f2bf(b.y); o[6] = f2bf(b.z); o[7] = f2bf(b.w);
  *((short8*)dst + off) = o;
}

// ---------------------------------------------------------------------------
// C = A * B^T, bf16 MFMA 16x16x32. BM=BN=128, BK=32, 256 threads (4 waves
// 2x2, wave tile 64x64: M_rep=N_rep=4). TRIPLE-buffered LDS (48 KB -> 3
// blocks/CU, 12 waves: inter-block overlap hides the barrier/vmcnt stalls,
// the m97 mechanism; tile-space table says 128^2 is optimal for this simple
// loop). One vmcnt(4) + one barrier per K-tile, distance-2 prefetch.
// Swizzle (64-B rows, 4x16B slots): slot ^= (row>>1)&3 on stage-source and
// ds_read (bank=(row&1)*16+slot*4 -> 2-way max = free). Bijective XCD
// block swizzle for L2 locality.
// MODE 2: C fp32 = acc*scale + rel_bias[gc-gr+ml-1] (scores)
// MODE 3: C fp32 = acc (PV)
// MODE 4: fused QKV: 1024-col slice 0 -> Q, 1 -> K, 2 -> V (ALL row-major)
// ---------------------------------------------------------------------------
template <int MODE>
__global__ __launch_bounds__(256, 3) void gemm_oc(
    const short* __restrict__ A, const short* __restrict__ Bt,
    void* __restrict__ C0, void* __restrict__ C1, void* __restrict__ C2,
    const float* __restrict__ rel_bias,
    int N, int K, long aZ, long bZ, long cZ, int Cdim, float scale, int ml) {
  __shared__ short sA[3][128 * 32];
  __shared__ short sB[3][128 * 32];
  const int tid = threadIdx.x, lane = tid & 63, wid = tid >> 6;

  // bijective XCD swizzle over the flat workgroup id
  const int gx = gridDim.x, gy = gridDim.y;
  const int nwg = gx * gy * (int)gridDim.z;
  const int f = ((int)blockIdx.z * gy + (int)blockIdx.y) * gx + (int)blockIdx.x;
  const int qq = nwg >> 3, rr = nwg & 7;
  const int xcd = f & 7, pos = f >> 3;
  const int lg = (xcd < rr ? xcd * (qq + 1) : rr * (qq + 1) + (xcd - rr) * qq) + pos;
  const int z = lg / (gx * gy);
  const int rem = lg - z * (gx * gy);
  const int bx = rem / gy, by = rem - bx * gy;  // by fastest: A-panel reuse

  const short* Az = A + (size_t)z * aZ;
  const short* Bz = Bt + (size_t)z * bZ;
  const int brow = bx * 128, bcol = by * 128;
  const int wr = wid >> 1, wc = wid & 1;
  const int lrow = lane & 15, kg = lane >> 4;

  // staging: half j covers rows j*64..+63; thread -> row tid>>2, slot tid&3
  const int t4 = tid >> 2;
  const int logslot = (tid & 3) ^ ((tid >> 3) & 3);  // pre-swizzled src slot
  const short* aSrc0 = Az + (size_t)(brow + t4) * K + logslot * 8;
  const short* aSrc1 = Az + (size_t)(brow + 64 + t4) * K + logslot * 8;
  const short* bSrc0 = Bz + (size_t)(bcol + t4) * K + logslot * 8;
  const short* bSrc1 = Bz + (size_t)(bcol + 64 + t4) * K + logslot * 8;
  const int d0 = wid * 512, d1 = 2048 + wid * 512;  // LDS dest (shorts)

  // ds_read: physical slot = kg ^ ((row>>1)&3); (row>>1)&3 == (lrow>>1)&3
  const int kOff = (kg ^ ((lrow >> 1) & 3)) * 8;
  const int aBase = (wr * 64 + lrow) * 32 + kOff;  // + m*512
  const int bBase = (wc * 64 + lrow) * 32 + kOff;  // + n*512

  short8 a[4], b[4];
  f32x4 acc[4][4] = {};

  short *pa0 = &sA[0][0], *pa1 = &sA[1][0], *pa2 = &sA[2][0];
  short *pb0 = &sB[0][0], *pb1 = &sB[1][0], *pb2 = &sB[2][0];

#define STG(PA, PB, T)                                    \
  do {                                                    \
    GLD16(aSrc0 + (size_t)(T) * 32, (PA) + d0);           \
    GLD16(aSrc1 + (size_t)(T) * 32, (PA) + d1);           \
    GLD16(bSrc0 + (size_t)(T) * 32, (PB) + d0);           \
    GLD16(bSrc1 + (size_t)(T) * 32, (PB) + d1);           \
  } while (0)
#define RD(PA, PB)                                                  \
  do {                                                              \
    _Pragma("unroll") for (int m = 0; m < 4; ++m)                   \
        a[m] = *(const short8*)&(PA)[aBase + m * 512];              \
    _Pragma("unroll") for (int n = 0; n < 4; ++n)                   \
        b[n] = *(const short8*)&(PB)[bBase + n * 512];              \
  } while (0)
#define MFMA16()                                                              \
  do {                                                                        \
    __builtin_amdgcn_s_setprio(1);                                            \
    _Pragma("unroll") for (int m = 0; m < 4; ++m)                             \
        _Pragma("unroll") for (int n = 0; n < 4; ++n)                         \
            acc[m][n] = __builtin_amdgcn_mfma_f32_16x16x32_bf16(              \
                a[m], b[n], acc[m][n], 0, 0, 0);                              \
    __builtin_amdgcn_s_setprio(0);                                            \
  } while (0)
#define ROT()                                                    \
  do {                                                           \
    short* q;                                                    \
    q = pa0; pa0 = pa1; pa1 = pa2; pa2 = q;                      \
    q = pb0; pb0 = pb1; pb1 = pb2; pb2 = q;                      \
  } while (0)

  // prologue: tiles 0,1 staged (8 loads outstanding)
  STG(pa0, pb0, 0);
  STG(pa1, pb1, 1);

  const int NT = K >> 5;  // K/32 tiles (32 or 64 here)
  for (int t = 0; t < NT - 2; ++t) {
    VMCNT4();   // drain tile t (tile t+1's 4 stay in flight)
    BAR();
    RD(pa0, pb0);
    STG(pa2, pb2, t + 2);   // buf freed by iter t-1's reads (pre-barrier)
    MFMA16();
    ROT();
  }
  // t = NT-2: no staging
  VMCNT4();
  BAR();
  RD(pa0, pb0);
  MFMA16();
  ROT();
  // t = NT-1
  VMCNT0();
  BAR();
  RD(pa0, pb0);
  MFMA16();

  // epilogue
#pragma unroll
  for (int m = 0; m < 4; ++m) {
#pragma unroll
    for (int n = 0; n < 4; ++n) {
#pragma unroll
      for (int r = 0; r < 4; ++r) {
        float v = acc[m][n][r];
        int gr = brow + wr * 64 + m * 16 + kg * 4 + r;
        int gc = bcol + wc * 64 + n * 16 + lrow;
        if constexpr (MODE == 2) {
          int idx = gc - gr + (ml - 1);
          idx = min(max(idx, 0), 2 * ml - 2);
          ((float*)C0 + (size_t)z * cZ)[(size_t)gr * N + gc] =
              v * scale + rel_bias[idx];
        } else if constexpr (MODE == 3) {
          ((float*)C0 + (size_t)z * cZ)[(size_t)gr * N + gc] = v;
        } else {  // MODE 4: fused QKV, 1024-col slices, ALL row-major
          int s = gc >> 10, cc = gc & 1023;
          short* dst = (s == 0) ? (short*)C0 : (s == 1) ? (short*)C1 : (short*)C2;
          dst[(size_t)gr * 1024 + cc] = f2bf(v);
        }
      }
    }
  }
#undef STG
#undef RD
#undef MFMA16
#undef ROT
}

// 64x64 LDS tile transpose: vin[b][c][e] (row-major [Cd][E]) -> vout[b][e][c]
__global__ __launch_bounds__(256) void transpose_v(const short* __restrict__ vin,
                                                   short* __restrict__ vout,
                                                   int Cd, int E) {
  __shared__ short t[64][72];
  const int c0 = blockIdx.x * 64, e0 = blockIdx.y * 64, b = blockIdx.z;
  const int tid = threadIdx.x;
  const int cr = tid >> 2;             // 0..63: input row within tile
  const int ec = (tid & 3) * 16;       // input col chunk
  const short* src = vin + ((size_t)b * Cd + c0 + cr) * E + e0 + ec;
  short8 v0 = *(const short8*)src;
  short8 v1 = *(const short8*)(src + 8);
#pragma unroll
  for (int j = 0; j < 8; ++j) t[ec + j][cr] = v0[j];
#pragma unroll
  for (int j = 0; j < 8; ++j) t[ec + 8 + j][cr] = v1[j];
  __syncthreads();
  const int er = tid >> 2;             // output row (e-dim)
  const int cc = (tid & 3) * 16;       // output col chunk (c-dim)
  short* dst = vout + ((size_t)b * E + e0 + er) * Cd + c0 + cc;
  *(short8*)dst = *(const short8*)&t[er][cc];
  *(short8*)(dst + 8) = *(const short8*)&t[er][cc + 8];
}

// Row softmax in place (rows of 2048) + bf16 copy for the PV GEMM.
__global__ __launch_bounds__(256) void softmax_rows(float* __restrict__ w,
                                                    short* __restrict__ wb, int Cd) {
  const size_t row = blockIdx.x;
  float4* p = (float4*)(w + row * (size_t)Cd);
  const int tid = threadIdx.x;
  float4 v0 = p[tid];
  float4 v1 = p[tid + 256];
  float mx = fmaxf(fmaxf(fmaxf(v0.x, v0.y), fmaxf(v0.z, v0.w)),
                   fmaxf(fmaxf(v1.x, v1.y), fmaxf(v1.z, v1.w)));
#pragma unroll
  for (int o = 32; o; o >>= 1) mx = fmaxf(mx, __shfl_xor(mx, o));
  __shared__ float red[8];
  const int wv = tid >> 6;
  if ((tid & 63) == 0) red[wv] = mx;
  __syncthreads();
  mx = fmaxf(fmaxf(red[0], red[1]), fmaxf(red[2], red[3]));
  v0.x = __expf(v0.x - mx); v0.y = __expf(v0.y - mx);
  v0.z = __expf(v0.z - mx); v0.w = __expf(v0.w - mx);
  v1.x = __expf(v1.x - mx); v1.y = __expf(v1.y - mx);
  v1.z = __expf(v1.z - mx); v1.w = __expf(v1.w - mx);
  float s = v0.x + v0.y + v0.z + v0.w + v1.x + v1.y + v1.z + v1.w;
#pragma unroll
  for (int o = 32; o; o >>= 1) s += __shfl_xor(s, o);
  if ((tid & 63) == 0) red[4 + wv] = s;
  __syncthreads();
  s = red[4] + red[5] + red[6] + red[7];
  float inv = 1.0f / s;
  v0.x *= inv; v0.y *= inv; v0.z *= inv; v0.w *= inv;
  v1.x *= inv; v1.y *= inv; v1.z *= inv; v1.w *= inv;
  p[tid] = v0;
  p[tid + 256] = v1;
  short4v b0, b1;
  b0[0] = f2bf(v0.x); b0[1] = f2bf(v0.y); b0[2] = f2bf(v0.z); b0[3] = f2bf(v0.w);
  b1[0] = f2bf(v1.x); b1[1] = f2bf(v1.y); b1[2] = f2bf(v1.z); b1[3] = f2bf(v1.w);
  short* wrow = wb + row * (size_t)Cd;
  *(short4v*)&wrow[tid * 4] = b0;
  *(short4v*)&wrow[1024 + tid * 4] = b1;
}

extern "C" void kernel_launch(void* const* d_in, const int* in_sizes, int n_in,
                              void* d_out, int out_size, void* d_ws, size_t ws_size,
                              hipStream_t stream) {
  const float* x = (const float*)d_in[0];
  const float* Wq = (const float*)d_in[1];
  const float* Wk = (const float*)d_in[2];
  const float* Wv = (const float*)d_in[3];
  const float* rb = (const float*)d_in[4];

  const int E = 1024;
  const int Mt = in_sizes[0] / E;           // B*C = 8192
  const int Cd = out_size / Mt - E;         // 2048
  const int B = Mt / Cd;                    // 4
  const int ml = (in_sizes[4] + 1) / 2;     // max_len = 2048
  const float scale = 1.0f / sqrtf((float)E);

  // workspace layout (bf16 = short), 70 MB
  short* xb = (short*)d_ws;                 // Mt*E (dead after QKV -> Vt)
  short* wqb = xb + (size_t)Mt * E;         // E*E x3
  short* wkb = wqb + (size_t)E * E;
  short* wvb = wkb + (size_t)E * E;
  short* Qb = wvb + (size_t)E * E;          // Mt*E
  short* Kb = Qb + (size_t)Mt * E;          // Mt*E
  short* Vrow = Kb + (size_t)Mt * E;        // Mt*E (V row-major)
  short* Vt = xb;                           // B*E*Cd = Mt*E (reuse xb)
  short* wbf = Qb;                          // Mt*Cd (reuse Q+K after scores)

  float* outp = (float*)d_out;              // Mt*E
  float* wts = outp + (size_t)Mt * E;       // Mt*Cd

  const int n0 = (Mt * E) / 8, n1 = (E * E) / 8;
  cvt_all<<<(n0 + 3 * n1 + 255) / 256, 256, 0, stream>>>(
      x, Wq, Wk, Wv, xb, wqb, wkb, wvb, n0, n1);

  dim3 blk(256);
  // fused QKV projection: A = xb (8192x1024), Bt = [Wq;Wk;Wv] (3072x1024)
  gemm_oc<4><<<dim3(Mt / 128, 3 * E / 128, 1), blk, 0, stream>>>(
      xb, wqb, Qb, Kb, Vrow, nullptr, 3 * E, E, 0, 0, 0, Cd, 0.f, ml);
  // scores = Q K^T * scale + bias (fp32 into weights region)
  gemm_oc<2><<<dim3(Cd / 128, Cd / 128, B), blk, 0, stream>>>(
      Qb, Kb, wts, nullptr, nullptr, rb, Cd, E, (long)Cd * E, (long)Cd * E,
      (long)Cd * Cd, Cd, scale, ml);
  softmax_rows<<<Mt, 256, 0, stream>>>(wts, wbf, Cd);
  // V -> V^T (xb region is dead now)
  transpose_v<<<dim3(Cd / 64, E / 64, B), 256, 0, stream>>>(Vrow, Vt, Cd, E);
  // out = weights @ V (A = bf16 weights, Bt = V^T)
  gemm_oc<3><<<dim3(Cd / 128, E / 128, B), blk, 0, stream>>>(
      wbf, Vt, outp, nullptr, nullptr, nullptr, E, Cd, (long)Cd * Cd,
      (long)E * Cd, (long)Cd * E, Cd, 0.f, ml);
}